// Round 8
// baseline (39.502 us; speedup 1.0000x reference)
//
#include <hip/hip_runtime.h>
#include <math.h>

#define BB 32
#define LL 128
#define DD 256
#define HH 1024            // 4*D
#define MAGIC 0x5F3C9A71u  // != 0xAA poison, != 0 fresh-alloc

__device__ __forceinline__ float waveReduceSum(float v) {
#pragma unroll
    for (int m = 32; m >= 1; m >>= 1) v += __shfl_xor(v, m, 64);
    return v;
}

// Single dispatch, 384 blocks x 256 threads.
//  - blocks 0..255: producers. 32 row-dots each (8192 rows total = a1|a2),
//    write s to wsS, release-store flag, exit. Full-chip HBM streaming.
//  - blocks 256..383: workers (batch b = w>>2, quarter q = w&3). Spin on the
//    8 producer flags of batch b, then: factorized-softmax stats (redundant
//    per quarter, cheap), full pooled[256] from L2/L3, quarter of FC+tanh.
// Flag staleness across graph replays is benign: guarded wsS data is
// recomputed bit-identically each replay (deterministic, same inputs).
__global__ __launch_bounds__(256) void fused_pc(
    const float* __restrict__ a1, const int* __restrict__ len1,
    const float* __restrict__ a2, const int* __restrict__ len2,
    const float* __restrict__ fcw, const float* __restrict__ fcb,
    const float* __restrict__ ww, float* __restrict__ out,
    float* __restrict__ wsS, unsigned* __restrict__ sflag)
{
    const int blk  = blockIdx.x;
    const int tid  = threadIdx.x;
    const int wave = tid >> 6;
    const int lane = tid & 63;

    if (blk < 256) {
        // ---------------- producer ----------------
        __shared__ __align__(16) float4 wws4[DD / 4];
        if (tid < DD / 4) wws4[tid] = ((const float4*)ww)[tid];
        __syncthreads();

        const int rloc = tid >> 3;         // 0..31
        const int t    = tid & 7;          // 8 threads per row
        const int row  = blk * 32 + rloc;  // 0..8191
        const float* __restrict__ src = (row < 4096)
            ? a1 + (size_t)row * DD
            : a2 + (size_t)(row - 4096) * DD;

        float ax = 0.f, ay = 0.f, az = 0.f, aw = 0.f;
#pragma unroll
        for (int qq = 0; qq < 8; ++qq) {
            const int idx = qq * 8 + t;
            const float4 v = ((const float4*)src)[idx];
            const float4 wv = wws4[idx];
            ax += v.x * wv.x; ay += v.y * wv.y; az += v.z * wv.z; aw += v.w * wv.w;
        }
        float s = (ax + ay) + (az + aw);
        s += __shfl_xor(s, 1, 64);
        s += __shfl_xor(s, 2, 64);
        s += __shfl_xor(s, 4, 64);
        if (t == 0) wsS[row] = s;
        __syncthreads();
        __threadfence();
        if (tid == 0)
            __hip_atomic_store(&sflag[blk], MAGIC, __ATOMIC_RELEASE,
                               __HIP_MEMORY_SCOPE_AGENT);
        return;
    }

    // ---------------- worker ----------------
    const int w = blk - 256;               // 0..127
    const int b = w >> 2;                  // batch
    const int q = w & 3;                   // h-quarter

    __shared__ float s1[LL], s2[LL], E1[LL], E2m[LL];
    __shared__ float rsv[LL], csv[LL];
    __shared__ float redS[4], redM[4];
    __shared__ __align__(16) float4 ps4[DD / 4];

    // wait for this batch's 8 producer blocks (a1: b*4+k, a2: 128+b*4+k)
    if (tid < 8) {
        const int fi = (tid < 4) ? (b * 4 + tid) : (128 + b * 4 + (tid - 4));
        while (__hip_atomic_load(&sflag[fi], __ATOMIC_ACQUIRE,
                                 __HIP_MEMORY_SCOPE_AGENT) != MAGIC)
            __builtin_amdgcn_s_sleep(1);
    }
    __syncthreads();

    const int l1 = len1[b];
    const int l2 = len2[b];

    if (tid < LL) s1[tid]      = wsS[b * LL + tid];
    else          s2[tid - LL] = wsS[4096 + b * LL + (tid - LL)];
    __syncthreads();

    // stats: E1=e^{s1}, E2m=e^{-s2}; S1,S2 over valid entries
    {
        float v = 0.f;
        if (tid < LL) {
            const float e = expf(s1[tid]);
            E1[tid] = e;
            if (tid < l1) v = e;
        } else {
            const int j = tid - LL;
            const float e = expf(-s2[j]);
            E2m[j] = e;
            if (j < l2) v = e;
        }
        v = waveReduceSum(v);
        if (lane == 0) redS[wave] = v;     // waves 0,1 -> S1; 2,3 -> S2
    }
    __syncthreads();
    // global masked-pair count M over valid pairs
    {
        int cnt = 0;
        const int base = tid * 64;
#pragma unroll 4
        for (int k = 0; k < 64; ++k) {
            const int n = base + k;
            const int i = n >> 7, j = n & 127;
            if (i < l1 && j < l2 && fabsf(s1[i] - s2[j]) < 1e-7f) cnt++;
        }
        const float fcnt = waveReduceSum((float)cnt);
        if (lane == 0) redM[wave] = fcnt;
    }
    __syncthreads();
    const float S1   = redS[0] + redS[1];
    const float S2   = redS[2] + redS[3];
    const float Mtot = redM[0] + redM[1] + redM[2] + redM[3];
    const float dinv = 1.0f / (S1 * S2 - Mtot);

    // per-row / per-col masked counts -> rsv, csv (pre-scaled by dinv)
    {
        const int rr  = tid >> 1;          // 0..127
        const int sub = tid & 1;
        int c1 = 0, c2 = 0;
        if (rr < l1) {
            const float si = s1[rr];
            for (int j = sub; j < l2; j += 2)
                if (fabsf(si - s2[j]) < 1e-7f) c1++;
        }
        if (rr < l2) {
            const float sj = s2[rr];
            for (int i = sub; i < l1; i += 2)
                if (fabsf(s1[i] - sj) < 1e-7f) c2++;
        }
        c1 += __shfl_xor(c1, 1, 64);
        c2 += __shfl_xor(c2, 1, 64);
        if (sub == 0) {
            rsv[rr] = (rr < l1) ? (E1[rr]  * S2 - (float)c1) * dinv : 0.f;
            csv[rr] = (rr < l2) ? (E2m[rr] * S1 - (float)c2) * dinv : 0.f;
        }
    }
    __syncthreads();

    // pooled[d], d = tid (L2/L3-warm reads, coalesced)
    {
        const float* __restrict__ A1 = a1 + (size_t)b * LL * DD;
        const float* __restrict__ A2 = a2 + (size_t)b * LL * DD;
        float p = 0.f;
#pragma unroll 8
        for (int i = 0; i < LL; ++i)
            p += rsv[i] * A1[i * DD + tid] - csv[i] * A2[i * DD + tid];
        ((float*)ps4)[tid] = p;
    }
    __syncthreads();

    // FC + tanh for this quarter's 256 h rows; 16 threads per row, 16 passes
    {
        const int hl  = tid >> 4;          // 0..15
        const int t16 = tid & 15;
        const float4 u0 = ps4[t16];
        const float4 u1 = ps4[16 + t16];
        const float4 u2 = ps4[32 + t16];
        const float4 u3 = ps4[48 + t16];
        float* __restrict__ outb = out + (size_t)b * HH;
#pragma unroll 4
        for (int pass = 0; pass < 16; ++pass) {
            const int h = q * 256 + pass * 16 + hl;
            const float4* __restrict__ wrow = (const float4*)(fcw + (size_t)h * DD);
            const float4 v0 = wrow[t16];
            const float4 v1 = wrow[16 + t16];
            const float4 v2 = wrow[32 + t16];
            const float4 v3 = wrow[48 + t16];
            float acc = v0.x * u0.x + v0.y * u0.y + v0.z * u0.z + v0.w * u0.w;
            acc      += v1.x * u1.x + v1.y * u1.y + v1.z * u1.z + v1.w * u1.w;
            acc      += v2.x * u2.x + v2.y * u2.y + v2.z * u2.z + v2.w * u2.w;
            acc      += v3.x * u3.x + v3.y * u3.y + v3.z * u3.z + v3.w * u3.w;
            acc += __shfl_xor(acc, 1, 64);
            acc += __shfl_xor(acc, 2, 64);
            acc += __shfl_xor(acc, 4, 64);
            acc += __shfl_xor(acc, 8, 64);
            if (t16 == 0) outb[h] = tanhf(acc + fcb[h]);
        }
    }
}

extern "C" void kernel_launch(void* const* d_in, const int* in_sizes, int n_in,
                              void* d_out, int out_size, void* d_ws, size_t ws_size,
                              hipStream_t stream) {
    const float* a1   = (const float*)d_in[0];
    const int*   len1 = (const int*)d_in[1];
    const float* a2   = (const float*)d_in[2];
    const int*   len2 = (const int*)d_in[3];
    const float* fcw  = (const float*)d_in[4];
    const float* fcb  = (const float*)d_in[5];
    const float* ww   = (const float*)d_in[6];
    float* out = (float*)d_out;

    float*    wsS   = (float*)d_ws;              // 8192 floats (s1|s2)
    unsigned* sflag = (unsigned*)(wsS + 8192);   // 256 flags

    fused_pc<<<384, 256, 0, stream>>>(a1, len1, a2, len2, fcw, fcb, ww, out,
                                      wsS, sflag);
}

// Round 9
// 31.683 us; speedup vs baseline: 1.2468x; 1.2468x over previous
//
#include <hip/hip_runtime.h>
#include <math.h>

#define BB 32
#define LL 128
#define DD 256
#define HH 1024   // 4*D

__device__ __forceinline__ float waveReduceSum(float v) {
#pragma unroll
    for (int m = 32; m >= 1; m >>= 1) v += __shfl_xor(v, m, 64);
    return v;
}

// ---------------- K1: all 8192 row-dots, full-chip wide ----------------
__global__ __launch_bounds__(256) void sdots_kernel(
    const float* __restrict__ a1, const float* __restrict__ a2,
    const float* __restrict__ ww, float* __restrict__ wsS)
{
    const int tid = threadIdx.x;
    __shared__ __align__(16) float4 wws4[DD / 4];
    if (tid < DD / 4) wws4[tid] = ((const float4*)ww)[tid];
    __syncthreads();

    const int rloc = tid >> 3;         // 0..31
    const int t    = tid & 7;          // 8 threads per row
    const int row  = blockIdx.x * 32 + rloc;   // 0..8191
    const float* __restrict__ src = (row < 4096)
        ? a1 + (size_t)row * DD
        : a2 + (size_t)(row - 4096) * DD;

    float ax = 0.f, ay = 0.f, az = 0.f, aw = 0.f;
#pragma unroll
    for (int qq = 0; qq < 8; ++qq) {
        const int idx = qq * 8 + t;
        const float4 v  = ((const float4*)src)[idx];
        const float4 wv = wws4[idx];
        ax += v.x * wv.x; ay += v.y * wv.y; az += v.z * wv.z; aw += v.w * wv.w;
    }
    float s = (ax + ay) + (az + aw);
    s += __shfl_xor(s, 1, 64);
    s += __shfl_xor(s, 2, 64);
    s += __shfl_xor(s, 4, 64);
    if (t == 0) wsS[row] = s;
}

// ------- K2: per (batch b, quarter q): stats + pooled + quarter FC -------
// Factorized softmax: exp(s1_i - s2_j) = e^{s1_i} * e^{-s2_j}. Masked pairs
// (|we|<1e-7; includes all invalid pairs, we==0) contribute exp(-1e7)=0;
// their unmasked e^{we}~=1 value is removed by count subtraction.
// denom = S1*S2 - M. No global max: |s| small => no fp32 overflow.
__global__ __launch_bounds__(256) void rest_kernel(
    const float* __restrict__ a1, const int* __restrict__ len1,
    const float* __restrict__ a2, const int* __restrict__ len2,
    const float* __restrict__ fcw, const float* __restrict__ fcb,
    const float* __restrict__ wsS, float* __restrict__ out)
{
    const int q    = blockIdx.x;       // h-quarter 0..3
    const int b    = blockIdx.y;       // batch
    const int tid  = threadIdx.x;
    const int wave = tid >> 6;
    const int lane = tid & 63;

    __shared__ float s1[LL], s2[LL], E1[LL], E2m[LL];
    __shared__ float rsv[LL], csv[LL];
    __shared__ float redS[4], redM[4];
    __shared__ __align__(16) float4 ps4[DD / 4];

    const int l1 = len1[b];
    const int l2 = len2[b];

    if (tid < LL) s1[tid]      = wsS[b * LL + tid];
    else          s2[tid - LL] = wsS[4096 + b * LL + (tid - LL)];
    __syncthreads();

    // stats: E1=e^{s1}, E2m=e^{-s2}; S1,S2 over valid entries
    {
        float v = 0.f;
        if (tid < LL) {
            const float e = expf(s1[tid]);
            E1[tid] = e;
            if (tid < l1) v = e;
        } else {
            const int j = tid - LL;
            const float e = expf(-s2[j]);
            E2m[j] = e;
            if (j < l2) v = e;
        }
        v = waveReduceSum(v);
        if (lane == 0) redS[wave] = v;     // waves 0,1 -> S1; 2,3 -> S2
    }
    __syncthreads();
    // global masked-pair count M over valid pairs
    {
        int cnt = 0;
        const int base = tid * 64;
#pragma unroll 4
        for (int k = 0; k < 64; ++k) {
            const int n = base + k;
            const int i = n >> 7, j = n & 127;
            if (i < l1 && j < l2 && fabsf(s1[i] - s2[j]) < 1e-7f) cnt++;
        }
        const float fcnt = waveReduceSum((float)cnt);
        if (lane == 0) redM[wave] = fcnt;
    }
    __syncthreads();
    const float S1   = redS[0] + redS[1];
    const float S2   = redS[2] + redS[3];
    const float Mtot = redM[0] + redM[1] + redM[2] + redM[3];
    const float dinv = 1.0f / (S1 * S2 - Mtot);

    // per-row / per-col masked counts -> rsv, csv (pre-scaled by dinv)
    {
        const int rr  = tid >> 1;          // 0..127
        const int sub = tid & 1;
        int c1 = 0, c2 = 0;
        if (rr < l1) {
            const float si = s1[rr];
            for (int j = sub; j < l2; j += 2)
                if (fabsf(si - s2[j]) < 1e-7f) c1++;
        }
        if (rr < l2) {
            const float sj = s2[rr];
            for (int i = sub; i < l1; i += 2)
                if (fabsf(s1[i] - sj) < 1e-7f) c2++;
        }
        c1 += __shfl_xor(c1, 1, 64);
        c2 += __shfl_xor(c2, 1, 64);
        if (sub == 0) {
            rsv[rr] = (rr < l1) ? (E1[rr]  * S2 - (float)c1) * dinv : 0.f;
            csv[rr] = (rr < l2) ? (E2m[rr] * S1 - (float)c2) * dinv : 0.f;
        }
    }
    __syncthreads();

    // pooled[d], d = tid (L2/L3-warm, coalesced)
    {
        const float* __restrict__ A1 = a1 + (size_t)b * LL * DD;
        const float* __restrict__ A2 = a2 + (size_t)b * LL * DD;
        float p = 0.f;
#pragma unroll 8
        for (int i = 0; i < LL; ++i)
            p += rsv[i] * A1[i * DD + tid] - csv[i] * A2[i * DD + tid];
        ((float*)ps4)[tid] = p;
    }
    __syncthreads();

    // FC + tanh for this quarter's 256 h rows; 16 threads per row, 16 passes
    {
        const int hl  = tid >> 4;          // 0..15
        const int t16 = tid & 15;
        const float4 u0 = ps4[t16];
        const float4 u1 = ps4[16 + t16];
        const float4 u2 = ps4[32 + t16];
        const float4 u3 = ps4[48 + t16];
        float* __restrict__ outb = out + (size_t)b * HH;
#pragma unroll 4
        for (int pass = 0; pass < 16; ++pass) {
            const int h = q * 256 + pass * 16 + hl;
            const float4* __restrict__ wrow = (const float4*)(fcw + (size_t)h * DD);
            const float4 v0 = wrow[t16];
            const float4 v1 = wrow[16 + t16];
            const float4 v2 = wrow[32 + t16];
            const float4 v3 = wrow[48 + t16];
            float acc = v0.x * u0.x + v0.y * u0.y + v0.z * u0.z + v0.w * u0.w;
            acc      += v1.x * u1.x + v1.y * u1.y + v1.z * u1.z + v1.w * u1.w;
            acc      += v2.x * u2.x + v2.y * u2.y + v2.z * u2.z + v2.w * u2.w;
            acc      += v3.x * u3.x + v3.y * u3.y + v3.z * u3.z + v3.w * u3.w;
            acc += __shfl_xor(acc, 1, 64);
            acc += __shfl_xor(acc, 2, 64);
            acc += __shfl_xor(acc, 4, 64);
            acc += __shfl_xor(acc, 8, 64);
            if (t16 == 0) outb[h] = tanhf(acc + fcb[h]);
        }
    }
}

extern "C" void kernel_launch(void* const* d_in, const int* in_sizes, int n_in,
                              void* d_out, int out_size, void* d_ws, size_t ws_size,
                              hipStream_t stream) {
    const float* a1   = (const float*)d_in[0];
    const int*   len1 = (const int*)d_in[1];
    const float* a2   = (const float*)d_in[2];
    const int*   len2 = (const int*)d_in[3];
    const float* fcw  = (const float*)d_in[4];
    const float* fcb  = (const float*)d_in[5];
    const float* ww   = (const float*)d_in[6];
    float* out = (float*)d_out;

    float* wsS = (float*)d_ws;     // 8192 floats (s for a1 | a2)

    sdots_kernel<<<256, 256, 0, stream>>>(a1, a2, ww, wsS);
    rest_kernel<<<dim3(4, BB), 256, 0, stream>>>(a1, len1, a2, len2,
                                                 fcw, fcb, wsS, out);
}

// Round 10
// 18.019 us; speedup vs baseline: 2.1922x; 1.7583x over previous
//
#include <hip/hip_runtime.h>
#include <math.h>

#define BB 32
#define LL 128
#define DD 256
#define HH 1024   // 4*D

__device__ __forceinline__ float waveReduceSum(float v) {
#pragma unroll
    for (int m = 32; m >= 1; m >>= 1) v += __shfl_xor(v, m, 64);
    return v;
}

// Single dispatch, 128 blocks x 1024 threads; block (b = blk&31, q = blk>>5).
// Each block: full phases 1-4 for batch b (phase1 duplicates merge in the
// XCD's L2 because the 4 blocks of a batch land on the same XCD under
// round-robin dispatch), then quarter q of the FC+tanh (256KB of fcw).
// Factorized softmax: exp(s1_i - s2_j) = e^{s1_i} * e^{-s2_j}; masked pairs
// (|we|<1e-7, incl. all invalid with we==0) contribute exp(-1e7)=0 after
// masking; their unmasked e^{we}~=1 value is removed via count subtraction.
// denom = S1*S2 - M. No global max needed: |s| small => no fp32 overflow.
__global__ __launch_bounds__(1024) void batch_q_kernel(
    const float* __restrict__ a1, const int* __restrict__ len1,
    const float* __restrict__ a2, const int* __restrict__ len2,
    const float* __restrict__ fcw, const float* __restrict__ fcb,
    const float* __restrict__ ww, float* __restrict__ out)
{
    const int blk  = blockIdx.x;
    const int b    = blk & 31;     // batch
    const int q    = blk >> 5;     // h-quarter 0..3
    const int tid  = threadIdx.x;
    const int wave = tid >> 6;     // 0..15
    const int lane = tid & 63;

    __shared__ __align__(16) float4 wws4[DD / 4];
    __shared__ float s1[LL], s2[LL], E1[LL], E2m[LL];
    __shared__ float rsv[LL], csv[LL];
    __shared__ float part[1024];
    __shared__ float redS[16], redM[16];
    __shared__ __align__(16) float4 ps4[DD / 4];

    const int l1 = len1[b];
    const int l2 = len2[b];

    if (tid < DD / 4) wws4[tid] = ((const float4*)ww)[tid];
    __syncthreads();

    const float* __restrict__ A1 = a1 + (size_t)b * LL * DD;
    const float* __restrict__ A2 = a2 + (size_t)b * LL * DD;

    // ---- phase 1: 256 row-dots, 4 threads per row ----
    {
        const int r = tid >> 2;            // 0..255
        const int t = tid & 3;
        const float4* __restrict__ row = (const float4*)
            ((r < LL) ? (A1 + (size_t)r * DD) : (A2 + (size_t)(r - LL) * DD));
        float ax = 0.f, ay = 0.f, az = 0.f, aw = 0.f;
#pragma unroll
        for (int qq = 0; qq < 16; ++qq) {
            const int idx = qq * 4 + t;
            const float4 v = row[idx];
            const float4 w = wws4[idx];
            ax += v.x * w.x; ay += v.y * w.y; az += v.z * w.z; aw += v.w * w.w;
        }
        float s = (ax + ay) + (az + aw);
        s += __shfl_xor(s, 1, 64);
        s += __shfl_xor(s, 2, 64);
        if (t == 0) { if (r < LL) s1[r] = s; else s2[r - LL] = s; }
    }
    __syncthreads();

    // ---- phase 2: E1=e^{s1}, E2m=e^{-s2}; S1,S2 over valid; M = masked count ----
    {
        float v = 0.f;
        if (tid < LL) {
            const float e = expf(s1[tid]);
            E1[tid] = e;
            if (tid < l1) v = e;
        } else if (tid < 2 * LL) {
            const int j = tid - LL;
            const float e = expf(-s2[j]);
            E2m[j] = e;
            if (j < l2) v = e;
        }
        v = waveReduceSum(v);
        if (lane == 0) redS[wave] = v;     // waves 0,1 -> S1; waves 2,3 -> S2
    }
    __syncthreads();
    {
        int cnt = 0;
        const int base = tid * 16;
#pragma unroll
        for (int qq = 0; qq < 16; ++qq) {
            const int n = base + qq;
            const int i = n >> 7, j = n & 127;
            if (i < l1 && j < l2 && fabsf(s1[i] - s2[j]) < 1e-7f) cnt++;
        }
        float fcnt = waveReduceSum((float)cnt);
        if (lane == 0) redM[wave] = fcnt;
    }
    __syncthreads();
    const float S1 = redS[0] + redS[1];
    const float S2 = redS[2] + redS[3];
    float Mtot = 0.f;
#pragma unroll
    for (int w = 0; w < 16; ++w) Mtot += redM[w];
    const float dinv = 1.0f / (S1 * S2 - Mtot);

    // ---- phase 3: rs/cs with per-row masked counts (4 threads per row/col) ----
    {
        const int rr  = tid >> 2;          // 0..255
        const int sub = tid & 3;
        int c2 = 0;
        if (rr < LL) {
            if (rr < l1) {
                const float si = s1[rr];
#pragma unroll 4
                for (int k = 0; k < 32; ++k) {
                    const int j = sub + 4 * k;
                    if (j < l2 && fabsf(si - s2[j]) < 1e-7f) c2++;
                }
            }
        } else {
            const int jj = rr - LL;
            if (jj < l2) {
                const float sj = s2[jj];
#pragma unroll 4
                for (int k = 0; k < 32; ++k) {
                    const int i = sub + 4 * k;
                    if (i < l1 && fabsf(s1[i] - sj) < 1e-7f) c2++;
                }
            }
        }
        c2 += __shfl_xor(c2, 1, 64);
        c2 += __shfl_xor(c2, 2, 64);
        if (sub == 0) {
            if (rr < LL)
                rsv[rr] = (rr < l1) ? (E1[rr] * S2 - (float)c2) * dinv : 0.f;
            else
                csv[rr - LL] = (rr - LL < l2) ? (E2m[rr - LL] * S1 - (float)c2) * dinv : 0.f;
        }
    }
    __syncthreads();

    // ---- phase 4: pooled[d] (a1/a2 L2-hot after phase 1), 4 row-groups x 256 d ----
    {
        const int d = tid & 255;
        const int g = tid >> 8;            // 0..3
        float p = 0.f;
#pragma unroll 8
        for (int k = 0; k < 32; ++k) {
            const int i = g * 32 + k;
            p += rsv[i] * A1[i * DD + d] - csv[i] * A2[i * DD + d];
        }
        part[tid] = p;
    }
    __syncthreads();
    if (tid < DD) {
        ((float*)ps4)[tid] = part[tid] + part[256 + tid] + part[512 + tid] + part[768 + tid];
    }
    __syncthreads();

    // ---- phase 5: FC + tanh for quarter q: 256 h rows, 64 rows/pass, 4 passes ----
    {
        const int hl  = tid >> 4;          // 0..63
        const int t16 = tid & 15;
        const float4 u0 = ps4[t16];
        const float4 u1 = ps4[16 + t16];
        const float4 u2 = ps4[32 + t16];
        const float4 u3 = ps4[48 + t16];
        float* __restrict__ outb = out + (size_t)b * HH;
#pragma unroll
        for (int pass = 0; pass < 4; ++pass) {
            const int h = q * 256 + pass * 64 + hl;
            const float4* __restrict__ wrow = (const float4*)(fcw + (size_t)h * DD);
            const float4 v0 = wrow[t16];
            const float4 v1 = wrow[16 + t16];
            const float4 v2 = wrow[32 + t16];
            const float4 v3 = wrow[48 + t16];
            float acc = v0.x * u0.x + v0.y * u0.y + v0.z * u0.z + v0.w * u0.w;
            acc      += v1.x * u1.x + v1.y * u1.y + v1.z * u1.z + v1.w * u1.w;
            acc      += v2.x * u2.x + v2.y * u2.y + v2.z * u2.z + v2.w * u2.w;
            acc      += v3.x * u3.x + v3.y * u3.y + v3.z * u3.z + v3.w * u3.w;
            acc += __shfl_xor(acc, 1, 64);
            acc += __shfl_xor(acc, 2, 64);
            acc += __shfl_xor(acc, 4, 64);
            acc += __shfl_xor(acc, 8, 64);
            if (t16 == 0) outb[h] = tanhf(acc + fcb[h]);
        }
    }
}

extern "C" void kernel_launch(void* const* d_in, const int* in_sizes, int n_in,
                              void* d_out, int out_size, void* d_ws, size_t ws_size,
                              hipStream_t stream) {
    const float* a1   = (const float*)d_in[0];
    const int*   len1 = (const int*)d_in[1];
    const float* a2   = (const float*)d_in[2];
    const int*   len2 = (const int*)d_in[3];
    const float* fcw  = (const float*)d_in[4];
    const float* fcb  = (const float*)d_in[5];
    const float* ww   = (const float*)d_in[6];
    float* out = (float*)d_out;

    batch_q_kernel<<<128, 1024, 0, stream>>>(a1, len1, a2, len2, fcw, fcb, ww, out);
}

// Round 11
// 16.458 us; speedup vs baseline: 2.4001x; 1.0948x over previous
//
#include <hip/hip_runtime.h>
#include <math.h>

#define BB 32
#define LL 128
#define DD 256
#define HH 1024   // 4*D
#define A1STRIDE 65   // float4 units per cached a1 row (260 floats: +4 pad, 16B aligned)

__device__ __forceinline__ float waveReduceSum(float v) {
#pragma unroll
    for (int m = 32; m >= 1; m >>= 1) v += __shfl_xor(v, m, 64);
    return v;
}

// Single dispatch, 256 blocks x 1024 threads; block (b = blk&31, q8 = blk>>5).
// All 8 blocks of a batch land on the same XCD (blk%8==b%8 under round-robin),
// so duplicate a1/a2 reads merge in that XCD's L2. Each block: phases 1-4 for
// batch b (a1 cached in LDS during phase 1; phase 4 reads a1 from LDS, a2 from
// L2), then eighth q8 of FC+tanh (128 KB of fcw).
// Factorized softmax: exp(s1_i - s2_j) = e^{s1_i} * e^{-s2_j}; masked pairs
// (|we|<1e-7, incl. all invalid with we==0) contribute exp(-1e7)=0 after
// masking; their unmasked e^{we}~=1 value is removed via count subtraction.
// denom = S1*S2 - M. No global max needed: |s| small => no fp32 overflow.
__global__ __launch_bounds__(1024) void batch_oct_kernel(
    const float* __restrict__ a1, const int* __restrict__ len1,
    const float* __restrict__ a2, const int* __restrict__ len2,
    const float* __restrict__ fcw, const float* __restrict__ fcb,
    const float* __restrict__ ww, float* __restrict__ out)
{
    const int blk  = blockIdx.x;
    const int b    = blk & 31;     // batch
    const int q8   = blk >> 5;     // h-eighth 0..7
    const int tid  = threadIdx.x;
    const int wave = tid >> 6;     // 0..15
    const int lane = tid & 63;

    __shared__ __align__(16) float4 A1l[LL * A1STRIDE];   // 133 KB a1 cache
    __shared__ __align__(16) float4 wws4[DD / 4];
    __shared__ float s1[LL], s2[LL], E1[LL], E2m[LL];
    __shared__ float rsv[LL], csv[LL];
    __shared__ float part[1024];
    __shared__ float redS[16], redM[16];
    __shared__ __align__(16) float4 ps4[DD / 4];

    const int l1 = len1[b];
    const int l2 = len2[b];

    if (tid < DD / 4) wws4[tid] = ((const float4*)ww)[tid];
    __syncthreads();

    const float* __restrict__ A1 = a1 + (size_t)b * LL * DD;
    const float* __restrict__ A2 = a2 + (size_t)b * LL * DD;

    // ---- phase 1: 256 row-dots, 4 threads per row; a1 rows cached in LDS ----
    {
        const int r = tid >> 2;            // 0..255 (waves 0-7: a1, 8-15: a2)
        const int t = tid & 3;
        float ax = 0.f, ay = 0.f, az = 0.f, aw = 0.f;
        if (r < LL) {
            const float4* __restrict__ row = (const float4*)(A1 + (size_t)r * DD);
#pragma unroll
            for (int qq = 0; qq < 16; ++qq) {
                const int idx = qq * 4 + t;
                const float4 v = row[idx];
                A1l[r * A1STRIDE + idx] = v;
                const float4 w = wws4[idx];
                ax += v.x * w.x; ay += v.y * w.y; az += v.z * w.z; aw += v.w * w.w;
            }
        } else {
            const float4* __restrict__ row = (const float4*)(A2 + (size_t)(r - LL) * DD);
#pragma unroll
            for (int qq = 0; qq < 16; ++qq) {
                const int idx = qq * 4 + t;
                const float4 v = row[idx];
                const float4 w = wws4[idx];
                ax += v.x * w.x; ay += v.y * w.y; az += v.z * w.z; aw += v.w * w.w;
            }
        }
        float s = (ax + ay) + (az + aw);
        s += __shfl_xor(s, 1, 64);
        s += __shfl_xor(s, 2, 64);
        if (t == 0) { if (r < LL) s1[r] = s; else s2[r - LL] = s; }
    }
    __syncthreads();

    // ---- phase 2: E1=e^{s1}, E2m=e^{-s2}; S1,S2 over valid; M = masked count ----
    {
        float v = 0.f;
        if (tid < LL) {
            const float e = expf(s1[tid]);
            E1[tid] = e;
            if (tid < l1) v = e;
        } else if (tid < 2 * LL) {
            const int j = tid - LL;
            const float e = expf(-s2[j]);
            E2m[j] = e;
            if (j < l2) v = e;
        }
        v = waveReduceSum(v);
        if (lane == 0) redS[wave] = v;     // waves 0,1 -> S1; waves 2,3 -> S2
    }
    __syncthreads();
    {
        int cnt = 0;
        const int base = tid * 16;
#pragma unroll
        for (int qq = 0; qq < 16; ++qq) {
            const int n = base + qq;
            const int i = n >> 7, j = n & 127;
            if (i < l1 && j < l2 && fabsf(s1[i] - s2[j]) < 1e-7f) cnt++;
        }
        float fcnt = waveReduceSum((float)cnt);
        if (lane == 0) redM[wave] = fcnt;
    }
    __syncthreads();
    const float S1 = redS[0] + redS[1];
    const float S2 = redS[2] + redS[3];
    float Mtot = 0.f;
#pragma unroll
    for (int w = 0; w < 16; ++w) Mtot += redM[w];
    const float dinv = 1.0f / (S1 * S2 - Mtot);

    // ---- phase 3: rs/cs with per-row masked counts (4 threads per row/col) ----
    {
        const int rr  = tid >> 2;          // 0..255
        const int sub = tid & 3;
        int c2 = 0;
        if (rr < LL) {
            if (rr < l1) {
                const float si = s1[rr];
#pragma unroll 4
                for (int k = 0; k < 32; ++k) {
                    const int j = sub + 4 * k;
                    if (j < l2 && fabsf(si - s2[j]) < 1e-7f) c2++;
                }
            }
        } else {
            const int jj = rr - LL;
            if (jj < l2) {
                const float sj = s2[jj];
#pragma unroll 4
                for (int k = 0; k < 32; ++k) {
                    const int i = sub + 4 * k;
                    if (i < l1 && fabsf(s1[i] - sj) < 1e-7f) c2++;
                }
            }
        }
        c2 += __shfl_xor(c2, 1, 64);
        c2 += __shfl_xor(c2, 2, 64);
        if (sub == 0) {
            if (rr < LL)
                rsv[rr] = (rr < l1) ? (E1[rr] * S2 - (float)c2) * dinv : 0.f;
            else
                csv[rr - LL] = (rr - LL < l2) ? (E2m[rr - LL] * S1 - (float)c2) * dinv : 0.f;
        }
    }
    __syncthreads();

    // ---- phase 4: pooled[d]: a1 from LDS, a2 from L2; 4 row-groups x 256 d ----
    {
        const int d = tid & 255;
        const int g = tid >> 8;            // 0..3
        const float* __restrict__ A1s = (const float*)A1l;   // row i at i*260 floats
        float p = 0.f;
#pragma unroll 8
        for (int k = 0; k < 32; ++k) {
            const int i = g * 32 + k;
            p += rsv[i] * A1s[i * (A1STRIDE * 4) + d] - csv[i] * A2[i * DD + d];
        }
        part[tid] = p;
    }
    __syncthreads();
    if (tid < DD) {
        ((float*)ps4)[tid] = part[tid] + part[256 + tid] + part[512 + tid] + part[768 + tid];
    }
    __syncthreads();

    // ---- phase 5: FC + tanh for eighth q8: 128 h rows, 64 rows/pass, 2 passes ----
    {
        const int hl  = tid >> 4;          // 0..63
        const int t16 = tid & 15;
        const float4 u0 = ps4[t16];
        const float4 u1 = ps4[16 + t16];
        const float4 u2 = ps4[32 + t16];
        const float4 u3 = ps4[48 + t16];
        float* __restrict__ outb = out + (size_t)b * HH;
#pragma unroll
        for (int pass = 0; pass < 2; ++pass) {
            const int h = q8 * 128 + pass * 64 + hl;
            const float4* __restrict__ wrow = (const float4*)(fcw + (size_t)h * DD);
            const float4 v0 = wrow[t16];
            const float4 v1 = wrow[16 + t16];
            const float4 v2 = wrow[32 + t16];
            const float4 v3 = wrow[48 + t16];
            float acc = v0.x * u0.x + v0.y * u0.y + v0.z * u0.z + v0.w * u0.w;
            acc      += v1.x * u1.x + v1.y * u1.y + v1.z * u1.z + v1.w * u1.w;
            acc      += v2.x * u2.x + v2.y * u2.y + v2.z * u2.z + v2.w * u2.w;
            acc      += v3.x * u3.x + v3.y * u3.y + v3.z * u3.z + v3.w * u3.w;
            acc += __shfl_xor(acc, 1, 64);
            acc += __shfl_xor(acc, 2, 64);
            acc += __shfl_xor(acc, 4, 64);
            acc += __shfl_xor(acc, 8, 64);
            if (t16 == 0) outb[h] = tanhf(acc + fcb[h]);
        }
    }
}

extern "C" void kernel_launch(void* const* d_in, const int* in_sizes, int n_in,
                              void* d_out, int out_size, void* d_ws, size_t ws_size,
                              hipStream_t stream) {
    const float* a1   = (const float*)d_in[0];
    const int*   len1 = (const int*)d_in[1];
    const float* a2   = (const float*)d_in[2];
    const int*   len2 = (const int*)d_in[3];
    const float* fcw  = (const float*)d_in[4];
    const float* fcb  = (const float*)d_in[5];
    const float* ww   = (const float*)d_in[6];
    float* out = (float*)d_out;

    batch_oct_kernel<<<256, 1024, 0, stream>>>(a1, len1, a2, len2, fcw, fcb, ww, out);
}

// Round 12
// 15.002 us; speedup vs baseline: 2.6332x; 1.0971x over previous
//
#include <hip/hip_runtime.h>
#include <math.h>

#define BB 32
#define LL 128
#define DD 256
#define HH 1024   // 4*D
#define A1STRIDE 65   // float4 units per cached a1 row (260 floats: +4 pad)

__device__ __forceinline__ float waveReduceSum(float v) {
#pragma unroll
    for (int m = 32; m >= 1; m >>= 1) v += __shfl_xor(v, m, 64);
    return v;
}

// Single dispatch, 256 blocks x 1024 threads; block (b = blk&31, q8 = blk>>5).
// All 8 blocks of a batch land on the same XCD (blk%8==b%8 under round-robin),
// so duplicate a1/a2 reads merge in that XCD's L2. Each block: phases 1-4 for
// batch b (a1 cached in LDS during phase 1; phase 4 reads a1 from LDS, a2 from
// L2, float4-vectorized), then eighth q8 of FC+tanh (128 KB of fcw).
// Factorized softmax: exp(s1_i - s2_j) = e^{s1_i} * e^{-s2_j}; masked pairs
// (|we|<1e-7, incl. all invalid with we==0) contribute exp(-1e7)=0 after
// masking; their unmasked e^{we}~=1 value is removed via count subtraction.
// denom = S1*S2 - M, with M = sum of per-row masked counts over valid rows.
// No global max needed: |s| small => no fp32 overflow.
__global__ __launch_bounds__(1024) void batch_oct_kernel(
    const float* __restrict__ a1, const int* __restrict__ len1,
    const float* __restrict__ a2, const int* __restrict__ len2,
    const float* __restrict__ fcw, const float* __restrict__ fcb,
    const float* __restrict__ ww, float* __restrict__ out)
{
    const int blk  = blockIdx.x;
    const int b    = blk & 31;     // batch
    const int q8   = blk >> 5;     // h-eighth 0..7
    const int tid  = threadIdx.x;
    const int wave = tid >> 6;     // 0..15
    const int lane = tid & 63;

    __shared__ __align__(16) float4 A1l[LL * A1STRIDE];   // 133 KB a1 cache
    __shared__ __align__(16) float4 part4[1024];          // 16 KB
    __shared__ __align__(16) float4 wws4[DD / 4];
    __shared__ float s1[LL], s2[LL], E1[LL], E2m[LL];
    __shared__ float rsv[LL], csv[LL];
    __shared__ float redS[16], redM[16];
    __shared__ __align__(16) float4 ps4[DD / 4];

    const int l1 = len1[b];
    const int l2 = len2[b];

    if (tid < DD / 4) wws4[tid] = ((const float4*)ww)[tid];
    __syncthreads();

    const float* __restrict__ A1 = a1 + (size_t)b * LL * DD;
    const float* __restrict__ A2 = a2 + (size_t)b * LL * DD;

    // ---- phase 1: 256 row-dots, 4 threads per row; a1 rows cached in LDS ----
    {
        const int r = tid >> 2;            // 0..255 (first half a1, second a2)
        const int t = tid & 3;
        float ax = 0.f, ay = 0.f, az = 0.f, aw = 0.f;
        if (r < LL) {
            const float4* __restrict__ row = (const float4*)(A1 + (size_t)r * DD);
#pragma unroll
            for (int qq = 0; qq < 16; ++qq) {
                const int idx = qq * 4 + t;
                const float4 v = row[idx];
                A1l[r * A1STRIDE + idx] = v;
                const float4 w = wws4[idx];
                ax += v.x * w.x; ay += v.y * w.y; az += v.z * w.z; aw += v.w * w.w;
            }
        } else {
            const float4* __restrict__ row = (const float4*)(A2 + (size_t)(r - LL) * DD);
#pragma unroll
            for (int qq = 0; qq < 16; ++qq) {
                const int idx = qq * 4 + t;
                const float4 v = row[idx];
                const float4 w = wws4[idx];
                ax += v.x * w.x; ay += v.y * w.y; az += v.z * w.z; aw += v.w * w.w;
            }
        }
        float s = (ax + ay) + (az + aw);
        s += __shfl_xor(s, 1, 64);
        s += __shfl_xor(s, 2, 64);
        if (t == 0) { if (r < LL) s1[r] = s; else s2[r - LL] = s; }
    }
    __syncthreads();

    // ---- phase 2: E1=e^{s1}, E2m=e^{-s2}; S1,S2 over valid entries ----
    {
        float v = 0.f;
        if (tid < LL) {
            const float e = expf(s1[tid]);
            E1[tid] = e;
            if (tid < l1) v = e;
        } else if (tid < 2 * LL) {
            const int j = tid - LL;
            const float e = expf(-s2[j]);
            E2m[j] = e;
            if (j < l2) v = e;
        }
        v = waveReduceSum(v);
        if (lane == 0) redS[wave] = v;     // waves 0,1 -> S1; waves 2,3 -> S2
    }
    __syncthreads();

    // ---- phase 3a: per-row / per-col masked counts (4 threads per row/col) ----
    {
        const int rr  = tid >> 2;          // 0..255
        const int sub = tid & 3;
        int c = 0;
        if (rr < LL) {
            if (rr < l1) {
                const float si = s1[rr];
#pragma unroll 4
                for (int k = 0; k < 32; ++k) {
                    const int j = sub + 4 * k;
                    if (j < l2 && fabsf(si - s2[j]) < 1e-7f) c++;
                }
            }
        } else {
            const int jj = rr - LL;
            if (jj < l2) {
                const float sj = s2[jj];
#pragma unroll 4
                for (int k = 0; k < 32; ++k) {
                    const int i = sub + 4 * k;
                    if (i < l1 && fabsf(s1[i] - sj) < 1e-7f) c++;
                }
            }
        }
        c += __shfl_xor(c, 1, 64);
        c += __shfl_xor(c, 2, 64);
        if (sub == 0) {
            if (rr < LL) rsv[rr] = (float)c;       // raw row count for now
            else         csv[rr - LL] = (float)c;  // raw col count
        }
    }
    __syncthreads();

    // ---- phase 3b: Mtot = sum of row counts over valid rows -> dinv ----
    {
        float mc = (tid < LL && tid < l1) ? rsv[tid] : 0.f;
        mc = waveReduceSum(mc);
        if (lane == 0) redM[wave] = mc;
    }
    __syncthreads();
    const float S1 = redS[0] + redS[1];
    const float S2 = redS[2] + redS[3];
    const float Mtot = redM[0] + redM[1];      // only waves 0,1 have tid<LL
    const float dinv = 1.0f / (S1 * S2 - Mtot);

    // ---- phase 3c: finalize rsv/csv (pre-scaled by dinv) ----
    if (tid < LL)
        rsv[tid] = (tid < l1) ? (E1[tid] * S2 - rsv[tid]) * dinv : 0.f;
    else if (tid < 2 * LL) {
        const int j = tid - LL;
        csv[j] = (j < l2) ? (E2m[j] * S1 - csv[j]) * dinv : 0.f;
    }
    __syncthreads();

    // ---- phase 4: pooled, float4-vectorized: wave g owns rows 8g..8g+7 ----
    {
        const int d4 = tid & 63;           // float4 column 0..63
        const int g  = tid >> 6;           // 0..15
        const float4* __restrict__ A2v = (const float4*)A2;
        float4 acc = make_float4(0.f, 0.f, 0.f, 0.f);
#pragma unroll
        for (int k = 0; k < 8; ++k) {
            const int i = g * 8 + k;
            const float4 va = A1l[i * A1STRIDE + d4];
            const float4 vb = A2v[i * 64 + d4];
            const float r_ = rsv[i], c_ = csv[i];
            acc.x += r_ * va.x - c_ * vb.x;
            acc.y += r_ * va.y - c_ * vb.y;
            acc.z += r_ * va.z - c_ * vb.z;
            acc.w += r_ * va.w - c_ * vb.w;
        }
        part4[tid] = acc;
    }
    __syncthreads();
    if (tid < 64) {
        float4 p = part4[tid];
#pragma unroll
        for (int g2 = 1; g2 < 16; ++g2) {
            const float4 qv = part4[g2 * 64 + tid];
            p.x += qv.x; p.y += qv.y; p.z += qv.z; p.w += qv.w;
        }
        ps4[tid] = p;
    }
    __syncthreads();

    // ---- phase 5: FC + tanh for eighth q8: 128 h rows, 64 rows/pass, 2 passes ----
    {
        const int hl  = tid >> 4;          // 0..63
        const int t16 = tid & 15;
        const float4 u0 = ps4[t16];
        const float4 u1 = ps4[16 + t16];
        const float4 u2 = ps4[32 + t16];
        const float4 u3 = ps4[48 + t16];
        float* __restrict__ outb = out + (size_t)b * HH;
#pragma unroll
        for (int pass = 0; pass < 2; ++pass) {
            const int h = q8 * 128 + pass * 64 + hl;
            const float4* __restrict__ wrow = (const float4*)(fcw + (size_t)h * DD);
            const float4 v0 = wrow[t16];
            const float4 v1 = wrow[16 + t16];
            const float4 v2 = wrow[32 + t16];
            const float4 v3 = wrow[48 + t16];
            float acc = v0.x * u0.x + v0.y * u0.y + v0.z * u0.z + v0.w * u0.w;
            acc      += v1.x * u1.x + v1.y * u1.y + v1.z * u1.z + v1.w * u1.w;
            acc      += v2.x * u2.x + v2.y * u2.y + v2.z * u2.z + v2.w * u2.w;
            acc      += v3.x * u3.x + v3.y * u3.y + v3.z * u3.z + v3.w * u3.w;
            acc += __shfl_xor(acc, 1, 64);
            acc += __shfl_xor(acc, 2, 64);
            acc += __shfl_xor(acc, 4, 64);
            acc += __shfl_xor(acc, 8, 64);
            if (t16 == 0) outb[h] = tanhf(acc + fcb[h]);
        }
    }
}

extern "C" void kernel_launch(void* const* d_in, const int* in_sizes, int n_in,
                              void* d_out, int out_size, void* d_ws, size_t ws_size,
                              hipStream_t stream) {
    const float* a1   = (const float*)d_in[0];
    const int*   len1 = (const int*)d_in[1];
    const float* a2   = (const float*)d_in[2];
    const int*   len2 = (const int*)d_in[3];
    const float* fcw  = (const float*)d_in[4];
    const float* fcb  = (const float*)d_in[5];
    const float* ww   = (const float*)d_in[6];
    float* out = (float*)d_out;

    batch_oct_kernel<<<256, 1024, 0, stream>>>(a1, len1, a2, len2, fcw, fcb, ww, out);
}

// Round 13
// 14.169 us; speedup vs baseline: 2.7880x; 1.0588x over previous
//
#include <hip/hip_runtime.h>
#include <math.h>

#define BB 32
#define LL 128
#define DD 256
#define HH 1024   // 4*D
#define A1STRIDE 65   // float4 units per cached a1 row (260 floats: +4 pad)

__device__ __forceinline__ float waveReduceSum(float v) {
#pragma unroll
    for (int m = 32; m >= 1; m >>= 1) v += __shfl_xor(v, m, 64);
    return v;
}

// Single dispatch, 256 blocks x 1024 threads; block (b = blk&31, q8 = blk>>5).
// All 8 blocks of a batch land on the same XCD (blk%8==b%8 under round-robin),
// so duplicate a1/a2 reads merge in that XCD's L2. Each block: phases 1-4 for
// batch b (a1 cached in LDS during phase 1; phase 4 reads a1 from LDS, a2 from
// L2, float4-vectorized), then eighth q8 of FC+tanh (128 KB of fcw).
// Factorized softmax: exp(s1_i - s2_j) = e^{s1_i} * e^{-s2_j}; masked pairs
// (|we|<1e-7, incl. all invalid with we==0) contribute exp(-1e7)=0 after
// masking; their unmasked e^{we}~=1 value is removed via count subtraction.
// denom = S1*S2 - M, with M = sum of per-row masked counts over valid rows.
// No global max needed: |s| small => no fp32 overflow.
__global__ __launch_bounds__(1024) void batch_oct_kernel(
    const float* __restrict__ a1, const int* __restrict__ len1,
    const float* __restrict__ a2, const int* __restrict__ len2,
    const float* __restrict__ fcw, const float* __restrict__ fcb,
    const float* __restrict__ ww, float* __restrict__ out)
{
    const int blk  = blockIdx.x;
    const int b    = blk & 31;     // batch
    const int q8   = blk >> 5;     // h-eighth 0..7
    const int tid  = threadIdx.x;
    const int wave = tid >> 6;     // 0..15
    const int lane = tid & 63;

    __shared__ __align__(16) float4 A1l[LL * A1STRIDE];   // 133 KB a1 cache
    __shared__ __align__(16) float4 part4[1024];          // 16 KB
    __shared__ __align__(16) float4 wws4[DD / 4];
    __shared__ float s1[LL], s2[LL], E1[LL], E2m[LL];
    __shared__ float rsv[LL], csv[LL];
    __shared__ float redS[16], redM[16];
    __shared__ __align__(16) float4 ps4[DD / 4];

    const int l1 = len1[b];
    const int l2 = len2[b];

    if (tid < DD / 4) wws4[tid] = ((const float4*)ww)[tid];
    __syncthreads();

    const float* __restrict__ A1 = a1 + (size_t)b * LL * DD;
    const float* __restrict__ A2 = a2 + (size_t)b * LL * DD;

    // ---- phase 1: 256 row-dots, 4 threads per row; a1 rows cached in LDS ----
    {
        const int r = tid >> 2;            // 0..255 (first half a1, second a2)
        const int t = tid & 3;
        float ax = 0.f, ay = 0.f, az = 0.f, aw = 0.f;
        if (r < LL) {
            const float4* __restrict__ row = (const float4*)(A1 + (size_t)r * DD);
#pragma unroll
            for (int qq = 0; qq < 16; ++qq) {
                const int idx = qq * 4 + t;
                const float4 v = row[idx];
                A1l[r * A1STRIDE + idx] = v;
                const float4 w = wws4[idx];
                ax += v.x * w.x; ay += v.y * w.y; az += v.z * w.z; aw += v.w * w.w;
            }
        } else {
            const float4* __restrict__ row = (const float4*)(A2 + (size_t)(r - LL) * DD);
#pragma unroll
            for (int qq = 0; qq < 16; ++qq) {
                const int idx = qq * 4 + t;
                const float4 v = row[idx];
                const float4 w = wws4[idx];
                ax += v.x * w.x; ay += v.y * w.y; az += v.z * w.z; aw += v.w * w.w;
            }
        }
        float s = (ax + ay) + (az + aw);
        s += __shfl_xor(s, 1, 64);
        s += __shfl_xor(s, 2, 64);
        if (t == 0) { if (r < LL) s1[r] = s; else s2[r - LL] = s; }
    }
    __syncthreads();

    // ---- phase 2: E1=e^{s1}, E2m=e^{-s2}; S1,S2 over valid entries ----
    {
        float v = 0.f;
        if (tid < LL) {
            const float e = expf(s1[tid]);
            E1[tid] = e;
            if (tid < l1) v = e;
        } else if (tid < 2 * LL) {
            const int j = tid - LL;
            const float e = expf(-s2[j]);
            E2m[j] = e;
            if (j < l2) v = e;
        }
        v = waveReduceSum(v);
        if (lane == 0) redS[wave] = v;     // waves 0,1 -> S1; waves 2,3 -> S2
    }
    __syncthreads();

    // ---- phase 3a: per-row / per-col masked counts, runtime-bounded loops ----
    {
        const int rr  = tid >> 2;          // 0..255
        const int sub = tid & 3;
        int c = 0;
        if (rr < LL) {
            if (rr < l1) {
                const float si = s1[rr];
                for (int j = sub; j < l2; j += 4)
                    if (fabsf(si - s2[j]) < 1e-7f) c++;
            }
        } else {
            const int jj = rr - LL;
            if (jj < l2) {
                const float sj = s2[jj];
                for (int i = sub; i < l1; i += 4)
                    if (fabsf(s1[i] - sj) < 1e-7f) c++;
            }
        }
        c += __shfl_xor(c, 1, 64);
        c += __shfl_xor(c, 2, 64);
        if (sub == 0) {
            if (rr < LL) rsv[rr] = (float)c;       // raw row count
            else         csv[rr - LL] = (float)c;  // raw col count
        }
    }
    __syncthreads();

    // ---- phase 3b: Mtot = sum of row counts over valid rows -> dinv ----
    {
        float mc = (tid < LL && tid < l1) ? rsv[tid] : 0.f;
        mc = waveReduceSum(mc);
        if (lane == 0) redM[wave] = mc;
    }
    __syncthreads();
    const float S1 = redS[0] + redS[1];
    const float S2 = redS[2] + redS[3];
    const float Mtot = redM[0] + redM[1];      // only waves 0,1 have tid<LL
    const float dinv = 1.0f / (S1 * S2 - Mtot);

    // ---- phase 3c: finalize rsv/csv (pre-scaled by dinv) ----
    if (tid < LL)
        rsv[tid] = (tid < l1) ? (E1[tid] * S2 - rsv[tid]) * dinv : 0.f;
    else if (tid < 2 * LL) {
        const int j = tid - LL;
        csv[j] = (j < l2) ? (E2m[j] * S1 - csv[j]) * dinv : 0.f;
    }
    __syncthreads();

    // ---- phase 4: pooled, float4-vectorized: wave g owns rows 8g..8g+7 ----
    {
        const int d4 = tid & 63;           // float4 column 0..63
        const int g  = tid >> 6;           // 0..15
        const float4* __restrict__ A2v = (const float4*)A2;
        float4 acc = make_float4(0.f, 0.f, 0.f, 0.f);
#pragma unroll
        for (int k = 0; k < 8; ++k) {
            const int i = g * 8 + k;
            const float4 va = A1l[i * A1STRIDE + d4];
            const float4 vb = A2v[i * 64 + d4];
            const float r_ = rsv[i], c_ = csv[i];
            acc.x += r_ * va.x - c_ * vb.x;
            acc.y += r_ * va.y - c_ * vb.y;
            acc.z += r_ * va.z - c_ * vb.z;
            acc.w += r_ * va.w - c_ * vb.w;
        }
        part4[tid] = acc;
    }
    __syncthreads();
    // two-step partial reduction: 256 threads x 4, then 64 x 4
    if (tid < 256) {
        float4 p = part4[tid];
        const float4 p1 = part4[256 + tid];
        const float4 p2 = part4[512 + tid];
        const float4 p3 = part4[768 + tid];
        p.x += p1.x + p2.x + p3.x;
        p.y += p1.y + p2.y + p3.y;
        p.z += p1.z + p2.z + p3.z;
        p.w += p1.w + p2.w + p3.w;
        part4[tid] = p;
    }
    __syncthreads();
    if (tid < 64) {
        float4 p = part4[tid];
        const float4 p1 = part4[64 + tid];
        const float4 p2 = part4[128 + tid];
        const float4 p3 = part4[192 + tid];
        p.x += p1.x + p2.x + p3.x;
        p.y += p1.y + p2.y + p3.y;
        p.z += p1.z + p2.z + p3.z;
        p.w += p1.w + p2.w + p3.w;
        ps4[tid] = p;
    }
    __syncthreads();

    // ---- phase 5: FC + tanh for eighth q8: 128 h rows, 64 rows/pass, 2 passes ----
    {
        const int hl  = tid >> 4;          // 0..63
        const int t16 = tid & 15;
        const float4 u0 = ps4[t16];
        const float4 u1 = ps4[16 + t16];
        const float4 u2 = ps4[32 + t16];
        const float4 u3 = ps4[48 + t16];
        float* __restrict__ outb = out + (size_t)b * HH;
#pragma unroll
        for (int pass = 0; pass < 2; ++pass) {
            const int h = q8 * 128 + pass * 64 + hl;
            const float4* __restrict__ wrow = (const float4*)(fcw + (size_t)h * DD);
            const float4 v0 = wrow[t16];
            const float4 v1 = wrow[16 + t16];
            const float4 v2 = wrow[32 + t16];
            const float4 v3 = wrow[48 + t16];
            float acc = v0.x * u0.x + v0.y * u0.y + v0.z * u0.z + v0.w * u0.w;
            acc      += v1.x * u1.x + v1.y * u1.y + v1.z * u1.z + v1.w * u1.w;
            acc      += v2.x * u2.x + v2.y * u2.y + v2.z * u2.z + v2.w * u2.w;
            acc      += v3.x * u3.x + v3.y * u3.y + v3.z * u3.z + v3.w * u3.w;
            acc += __shfl_xor(acc, 1, 64);
            acc += __shfl_xor(acc, 2, 64);
            acc += __shfl_xor(acc, 4, 64);
            acc += __shfl_xor(acc, 8, 64);
            if (t16 == 0) outb[h] = tanhf(acc + fcb[h]);
        }
    }
}

extern "C" void kernel_launch(void* const* d_in, const int* in_sizes, int n_in,
                              void* d_out, int out_size, void* d_ws, size_t ws_size,
                              hipStream_t stream) {
    const float* a1   = (const float*)d_in[0];
    const int*   len1 = (const int*)d_in[1];
    const float* a2   = (const float*)d_in[2];
    const int*   len2 = (const int*)d_in[3];
    const float* fcw  = (const float*)d_in[4];
    const float* fcb  = (const float*)d_in[5];
    const float* ww   = (const float*)d_in[6];
    float* out = (float*)d_out;

    batch_oct_kernel<<<256, 1024, 0, stream>>>(a1, len1, a2, len2, fcw, fcb, ww, out);
}